// Round 7
// baseline (11.625 us; speedup 1.0000x reference)
//
#include <hip/hip_runtime.h>
#include <math.h>

#define REG_MAX 16
#define NUM_CLASSES 20
#define CCH (4 * REG_MAX + NUM_CLASSES)   // 84 channels per cell

// Kernel 1: TWO threads per (b,g) anchor (pair = lanes 2a, 2a+1).
//  - half 0: DFL sides 0,1 + BCE classes 0..11
//  - half 1: DFL sides 2,3 + BCE classes 12..19
// Pair merge via __shfl_xor(.,1); per-anchor result kept on even lane only.
// Block = 1 wave (64 threads) -> 32 anchors/block, 200 blocks over 200 CUs.
__global__ __launch_bounds__(64)
void yolo_loss_main(const float* __restrict__ pred0,
                    const float* __restrict__ pred1,
                    const float* __restrict__ pred2,
                    const float* __restrict__ boxes,
                    const int*   __restrict__ labels,
                    const int*   __restrict__ img_size_p,
                    float* __restrict__ partials,   // [gridDim.x][3]
                    int B, int G)
{
    const int tid  = blockIdx.x * 64 + threadIdx.x;
    const int a    = tid >> 1;          // anchor index
    const int half = tid & 1;           // which half of the pair
    const int N    = B * G;

    float box_l = 0.f, cls_l = 0.f, dfl_l = 0.f;

    if (a < N) {
        const int b = a / G;
        const float4 bv = *reinterpret_cast<const float4*>(boxes + (size_t)a * 4);
        const int lab = labels[a];
        const float cx = bv.x, cy = bv.y, w = bv.z, h = bv.w;

        const float img = (float)(*img_size_p);
        const float scale = fmaxf(w, h) * img;
        const int lvl = (scale < 64.f) ? 0 : ((scale < 128.f) ? 1 : 2);

        const float* pred; int W, H;
        if (lvl == 0)      { pred = pred0; W = 80; H = 80; }
        else if (lvl == 1) { pred = pred1; W = 40; H = 40; }
        else               { pred = pred2; W = 20; H = 20; }
        const float Wf = (float)W, Hf = (float)H;
        const float invW = __fdividef(1.f, Wf);
        const float invH = __fdividef(1.f, Hf);

        int gx = (int)floorf(cx * Wf); gx = min(max(gx, 0), W - 1);
        int gy = (int)floorf(cy * Hf); gy = min(max(gy, 0), H - 1);

        // cell base: 84 floats, 336B => 16B aligned
        const float* cell = pred + ((size_t)((b * H + gy) * W + gx)) * CCH;

        const float ax = (float)gx + 0.5f, ay = (float)gy + 0.5f;
        const float x1 = (cx - w * 0.5f) * Wf, x2 = (cx + w * 0.5f) * Wf;
        const float y1 = (cy - h * 0.5f) * Hf, y2 = (cy + h * 0.5f) * Hf;

        float t[4];
        t[0] = fmaxf(ax - x1, 0.f);
        t[1] = fmaxf(ay - y1, 0.f);
        t[2] = fmaxf(x2 - ax, 0.f);
        t[3] = fmaxf(y2 - ay, 0.f);

        // ---- my two DFL sides (16-bin softmax each) ----
        const int s_base = half * 2;
        const float4* dl = reinterpret_cast<const float4*>(cell + s_base * REG_MAX);
        float d_own[2];
        float dfl_own = 0.f;
        #pragma unroll
        for (int s = 0; s < 2; ++s) {
            float v[16];
            #pragma unroll
            for (int q = 0; q < 4; ++q) {
                float4 f = dl[s * 4 + q];
                v[4*q+0] = f.x; v[4*q+1] = f.y; v[4*q+2] = f.z; v[4*q+3] = f.w;
            }
            float m = v[0];
            #pragma unroll
            for (int j = 1; j < 16; ++j) m = fmaxf(m, v[j]);
            float se = 0.f, swe = 0.f;
            #pragma unroll
            for (int j = 0; j < 16; ++j) {
                float e = __expf(v[j] - m);          // arg <= 0: safe
                se  += e;
                swe += e * (float)j;
            }
            const float lse = m + __logf(se);        // se >= 1: safe
            int tb = (int)t[s_base + s];             // >=0, trunc == floor
            tb = min(tb, REG_MAX - 1);
            dfl_own += -(v[tb] - lse);               // -log_softmax[tb]
            d_own[s] = __fdividef(swe, se);
        }

        // ---- my BCE classes: half 0 -> q=0..2 (cls 0..11), half 1 -> q=3..4 ----
        const float* cl = cell + 4 * REG_MAX;        // 16B aligned
        const int q_lo = half ? 3 : 0;
        const int q_hi = half ? 5 : 3;
        float bce_lin = 0.f;
        float prod = 1.f;                            // Pi (1 + e^-|x|) <= 2^12
        for (int q = q_lo; q < q_hi; ++q) {
            float4 f = reinterpret_cast<const float4*>(cl)[q];
            float xs[4] = { f.x, f.y, f.z, f.w };
            #pragma unroll
            for (int r = 0; r < 4; ++r) {
                const int c = 4*q + r;
                const float x = xs[r];
                bce_lin += fmaxf(x, 0.f) - ((c == lab) ? x : 0.f);
                prod    *= 1.f + __expf(-fabsf(x));
            }
        }
        const float bce_own = bce_lin + __logf(prod);

        // ---- pair merge ----
        const float dA = __shfl_xor(d_own[0], 1);
        const float dB = __shfl_xor(d_own[1], 1);
        float d_exp[4];
        if (half == 0) { d_exp[0] = d_own[0]; d_exp[1] = d_own[1]; d_exp[2] = dA; d_exp[3] = dB; }
        else           { d_exp[0] = dA;       d_exp[1] = dB;       d_exp[2] = d_own[0]; d_exp[3] = d_own[1]; }
        const float dfl_pair = dfl_own + __shfl_xor(dfl_own, 1);
        const float bce_pair = bce_own + __shfl_xor(bce_own, 1);

        // ---- GIoU box loss (computed redundantly by both halves) ----
        const float x1p = (ax - d_exp[0]) * invW;
        const float y1p = (ay - d_exp[1]) * invH;
        const float x2p = (ax + d_exp[2]) * invW;
        const float y2p = (ay + d_exp[3]) * invH;
        const float gx1 = cx - w * 0.5f, gy1 = cy - h * 0.5f;
        const float gx2 = cx + w * 0.5f, gy2 = cy + h * 0.5f;

        const float iw = fmaxf(fminf(x2p, gx2) - fmaxf(x1p, gx1), 0.f);
        const float ih = fmaxf(fminf(y2p, gy2) - fmaxf(y1p, gy1), 0.f);
        const float inter  = iw * ih;
        const float area_p = (x2p - x1p) * (y2p - y1p);
        const float area_g = (gx2 - gx1) * (gy2 - gy1);
        const float uni    = area_p + area_g - inter;
        const float areac  = (fmaxf(x2p, gx2) - fminf(x1p, gx1)) *
                             (fmaxf(y2p, gy2) - fminf(y1p, gy1));
        const float giou = __fdividef(inter, uni)
                         - __fdividef(areac - uni, areac);

        // keep per-anchor contribution on even lane only
        if (half == 0) {
            box_l = 1.f - giou;
            dfl_l = dfl_pair * 0.25f;
            cls_l = bce_pair * (1.f / NUM_CLASSES);
        }
    }

    // ---- wave reduction (block = exactly 1 wave of 64) ----
    #pragma unroll
    for (int off = 32; off > 0; off >>= 1) {
        box_l += __shfl_down(box_l, off);
        cls_l += __shfl_down(cls_l, off);
        dfl_l += __shfl_down(dfl_l, off);
    }
    if (threadIdx.x == 0) {
        partials[blockIdx.x * 3 + 0] = box_l;
        partials[blockIdx.x * 3 + 1] = cls_l;
        partials[blockIdx.x * 3 + 2] = dfl_l;
    }
}

// Kernel 2: reduce per-block partials, write the 4 outputs.
__global__ __launch_bounds__(64)
void yolo_loss_final(const float* __restrict__ partials, int nblocks,
                     float* __restrict__ out, int N)
{
    const int lane = threadIdx.x;
    float s0 = 0.f, s1 = 0.f, s2 = 0.f;
    for (int j = lane; j < nblocks; j += 64) {
        s0 += partials[j * 3 + 0];
        s1 += partials[j * 3 + 1];
        s2 += partials[j * 3 + 2];
    }
    #pragma unroll
    for (int off = 32; off > 0; off >>= 1) {
        s0 += __shfl_down(s0, off);
        s1 += __shfl_down(s1, off);
        s2 += __shfl_down(s2, off);
    }
    if (lane == 0) {
        const float invN = 1.f / (float)N;
        const float box = s0 * invN, cls = s1 * invN, dfl = s2 * invN;
        out[0] = 5.0f * box + 0.5f * cls + 1.5f * dfl;   // total
        out[1] = box;
        out[2] = cls;
        out[3] = dfl;
    }
}

extern "C" void kernel_launch(void* const* d_in, const int* in_sizes, int n_in,
                              void* d_out, int out_size, void* d_ws, size_t ws_size,
                              hipStream_t stream)
{
    const float* pred0  = (const float*)d_in[0];
    const float* pred1  = (const float*)d_in[1];
    const float* pred2  = (const float*)d_in[2];
    const float* boxes  = (const float*)d_in[3];
    const int*   labels = (const int*)d_in[4];
    const int*   imgsz  = (const int*)d_in[5];
    float* out = (float*)d_out;

    const int B = in_sizes[0] / (80 * 80 * CCH);   // 32
    const int G = in_sizes[3] / (4 * B);           // 200
    const int N = B * G;                           // 6400

    float* partials = (float*)d_ws;                // nblocks*3 floats

    const int block = 64;
    const int nblocks = (2 * N + block - 1) / block;   // 200 (2 threads/anchor)

    yolo_loss_main<<<nblocks, block, 0, stream>>>(
        pred0, pred1, pred2, boxes, labels, imgsz, partials, B, G);
    yolo_loss_final<<<1, 64, 0, stream>>>(partials, nblocks, out, N);
}

// Round 8
// 11.036 us; speedup vs baseline: 1.0534x; 1.0534x over previous
//
#include <hip/hip_runtime.h>
#include <math.h>

#define REG_MAX 16
#define NUM_CLASSES 20
#define CCH (4 * REG_MAX + NUM_CLASSES)   // 84 channels per cell

// Kernel 1: one thread per (b,g) anchor; block = exactly 1 wave (64 threads)
// -> 100 blocks over 100 CUs, pure shuffle reduce, no LDS barrier.
// Fast math: __expf/__logf; BCE uses log(prod(1+e^-|x|)) -> 2 logs not 20;
// divides via __fdividef / reciprocal-mul.
__global__ __launch_bounds__(64)
void yolo_loss_main(const float* __restrict__ pred0,
                    const float* __restrict__ pred1,
                    const float* __restrict__ pred2,
                    const float* __restrict__ boxes,
                    const int*   __restrict__ labels,
                    const int*   __restrict__ img_size_p,
                    float* __restrict__ partials,   // [gridDim.x][3]
                    int B, int G)
{
    const int i = blockIdx.x * 64 + threadIdx.x;
    const int N = B * G;

    float box_l = 0.f, cls_l = 0.f, dfl_l = 0.f;

    if (i < N) {
        const int b = i / G;
        // boxes is (B,G,4) contiguous -> aligned float4
        const float4 bv = *reinterpret_cast<const float4*>(boxes + (size_t)i * 4);
        const int lab = labels[i];
        const float cx = bv.x, cy = bv.y, w = bv.z, h = bv.w;

        const float img = (float)(*img_size_p);
        const float scale = fmaxf(w, h) * img;
        const int lvl = (scale < 64.f) ? 0 : ((scale < 128.f) ? 1 : 2);

        const float* pred; int W, H;
        if (lvl == 0)      { pred = pred0; W = 80; H = 80; }
        else if (lvl == 1) { pred = pred1; W = 40; H = 40; }
        else               { pred = pred2; W = 20; H = 20; }
        const float Wf = (float)W, Hf = (float)H;
        const float invW = __frcp_rn(Wf);   // W is a power-of-2-scaled exact value (80,40,20)
        const float invH = __frcp_rn(Hf);

        int gx = (int)floorf(cx * Wf); gx = min(max(gx, 0), W - 1);
        int gy = (int)floorf(cy * Hf); gy = min(max(gy, 0), H - 1);

        // cell base: 84 floats, 336B => 16B aligned
        const float* cell = pred + ((size_t)((b * H + gy) * W + gx)) * CCH;

        const float ax = (float)gx + 0.5f, ay = (float)gy + 0.5f;
        const float x1 = (cx - w * 0.5f) * Wf, x2 = (cx + w * 0.5f) * Wf;
        const float y1 = (cy - h * 0.5f) * Hf, y2 = (cy + h * 0.5f) * Hf;

        float t[4];
        t[0] = fmaxf(ax - x1, 0.f);
        t[1] = fmaxf(ay - y1, 0.f);
        t[2] = fmaxf(x2 - ax, 0.f);
        t[3] = fmaxf(y2 - ay, 0.f);

        // ---- DFL + expected distances (4 sides x 16-bin softmax) ----
        float d_exp[4];
        float dfl_sum = 0.f;
        #pragma unroll
        for (int s = 0; s < 4; ++s) {
            const float4* dl = reinterpret_cast<const float4*>(cell + s * REG_MAX);
            float v[16];
            #pragma unroll
            for (int q = 0; q < 4; ++q) {
                float4 f = dl[q];
                v[4*q+0] = f.x; v[4*q+1] = f.y; v[4*q+2] = f.z; v[4*q+3] = f.w;
            }
            float m = v[0];
            #pragma unroll
            for (int j = 1; j < 16; ++j) m = fmaxf(m, v[j]);
            float se = 0.f, swe = 0.f;
            #pragma unroll
            for (int j = 0; j < 16; ++j) {
                float e = __expf(v[j] - m);          // arg <= 0: safe
                se  += e;
                swe += e * (float)j;
            }
            const float lse = m + __logf(se);        // se >= 1: safe
            int tb = (int)t[s];                      // t >= 0, trunc == floor
            tb = min(max(tb, 0), REG_MAX - 1);
            dfl_sum += -(v[tb] - lse);               // -log_softmax[tb]
            d_exp[s] = __fdividef(swe, se);
        }
        dfl_l = dfl_sum * 0.25f;

        // ---- GIoU box loss ----
        const float x1p = (ax - d_exp[0]) * invW;
        const float y1p = (ay - d_exp[1]) * invH;
        const float x2p = (ax + d_exp[2]) * invW;
        const float y2p = (ay + d_exp[3]) * invH;
        const float gx1 = cx - w * 0.5f, gy1 = cy - h * 0.5f;
        const float gx2 = cx + w * 0.5f, gy2 = cy + h * 0.5f;

        const float iw = fmaxf(fminf(x2p, gx2) - fmaxf(x1p, gx1), 0.f);
        const float ih = fmaxf(fminf(y2p, gy2) - fmaxf(y1p, gy1), 0.f);
        const float inter  = iw * ih;
        const float area_p = (x2p - x1p) * (y2p - y1p);
        const float area_g = (gx2 - gx1) * (gy2 - gy1);
        const float uni    = area_p + area_g - inter;
        const float areac  = (fmaxf(x2p, gx2) - fminf(x1p, gx1)) *
                             (fmaxf(y2p, gy2) - fminf(y1p, gy1));
        const float giou = __fdividef(inter, uni)
                         - __fdividef(areac - uni, areac);
        box_l = 1.f - giou;

        // ---- BCE classification loss ----
        // sum log1p(e^-|x|) = log(prod(1+e^-|x|)); terms in (1,2], prod<=2^20.
        const float* cl = cell + 4 * REG_MAX;   // +256B, 16B aligned
        float bce_lin = 0.f;
        float prodA = 1.f, prodB = 1.f;         // two chains for ILP
        #pragma unroll
        for (int q = 0; q < 5; ++q) {
            float4 f = reinterpret_cast<const float4*>(cl)[q];
            float xs[4] = { f.x, f.y, f.z, f.w };
            #pragma unroll
            for (int r = 0; r < 4; ++r) {
                const int c = 4*q + r;
                const float x = xs[r];
                bce_lin += fmaxf(x, 0.f) - ((c == lab) ? x : 0.f);
                const float term = 1.f + __expf(-fabsf(x));
                if (r & 1) prodA *= term; else prodB *= term;
            }
        }
        const float bce = bce_lin + __logf(prodA) + __logf(prodB);
        cls_l = bce * (1.f / NUM_CLASSES);
    }

    // ---- wave reduction (block = exactly 1 wave of 64) ----
    #pragma unroll
    for (int off = 32; off > 0; off >>= 1) {
        box_l += __shfl_down(box_l, off);
        cls_l += __shfl_down(cls_l, off);
        dfl_l += __shfl_down(dfl_l, off);
    }
    if (threadIdx.x == 0) {
        partials[blockIdx.x * 3 + 0] = box_l;
        partials[blockIdx.x * 3 + 1] = cls_l;
        partials[blockIdx.x * 3 + 2] = dfl_l;
    }
}

// Kernel 2: reduce per-block partials, write the 4 outputs.
__global__ __launch_bounds__(64)
void yolo_loss_final(const float* __restrict__ partials, int nblocks,
                     float* __restrict__ out, int N)
{
    const int lane = threadIdx.x;
    float s0 = 0.f, s1 = 0.f, s2 = 0.f;
    for (int j = lane; j < nblocks; j += 64) {
        s0 += partials[j * 3 + 0];
        s1 += partials[j * 3 + 1];
        s2 += partials[j * 3 + 2];
    }
    #pragma unroll
    for (int off = 32; off > 0; off >>= 1) {
        s0 += __shfl_down(s0, off);
        s1 += __shfl_down(s1, off);
        s2 += __shfl_down(s2, off);
    }
    if (lane == 0) {
        const float invN = 1.f / (float)N;
        const float box = s0 * invN, cls = s1 * invN, dfl = s2 * invN;
        out[0] = 5.0f * box + 0.5f * cls + 1.5f * dfl;   // total
        out[1] = box;
        out[2] = cls;
        out[3] = dfl;
    }
}

extern "C" void kernel_launch(void* const* d_in, const int* in_sizes, int n_in,
                              void* d_out, int out_size, void* d_ws, size_t ws_size,
                              hipStream_t stream)
{
    const float* pred0  = (const float*)d_in[0];
    const float* pred1  = (const float*)d_in[1];
    const float* pred2  = (const float*)d_in[2];
    const float* boxes  = (const float*)d_in[3];
    const int*   labels = (const int*)d_in[4];
    const int*   imgsz  = (const int*)d_in[5];
    float* out = (float*)d_out;

    const int B = in_sizes[0] / (80 * 80 * CCH);   // 32
    const int G = in_sizes[3] / (4 * B);           // 200
    const int N = B * G;                           // 6400

    float* partials = (float*)d_ws;                // nblocks*3 floats

    const int block = 64;
    const int nblocks = (N + block - 1) / block;   // 100

    yolo_loss_main<<<nblocks, block, 0, stream>>>(
        pred0, pred1, pred2, boxes, labels, imgsz, partials, B, G);
    yolo_loss_final<<<1, 64, 0, stream>>>(partials, nblocks, out, N);
}